// Round 4
// baseline (563.476 us; speedup 1.0000x reference)
//
#include <hip/hip_runtime.h>
#include <hip/hip_bf16.h>

#define NN 50000
#define NE 800000

typedef __bf16 bf16_t;
typedef bf16_t bf16x8 __attribute__((ext_vector_type(8)));
typedef float f32x4 __attribute__((ext_vector_type(4)));

// fast gelu: x * sigmoid(1.595769x + 0.0713548x^3), max abs err vs erf-gelu ~4e-4
__device__ __forceinline__ float gelu_f(float x) {
    float v = x * fmaf(x * x, 0.07135481627f, 1.595769122f);
    float e = __expf(-v);
    return x * __builtin_amdgcn_rcpf(1.0f + e);
}

// ---------------- weight folding into MFMA B-fragment order ----------------
// idx = ((nt*nkc + (k>>5))*64 + ((k>>3)&3)*16 + lrow)*8 + (k&7), n = nt*16+lrow
__device__ void fold_frag(int K, const float* W, const float* g, const float* b,
                          const float* mu, const float* v, const float* c,
                          bf16_t* Wf, float* cb, int tid, float* part) {
    const int n = tid & 63, kc = tid >> 6;
    const int nt = n >> 4, lrow = n & 15, nkc = K >> 5;
    const int kq = K >> 2, k0 = kc * kq, k1 = k0 + kq;
    float acc = 0.f;
    for (int k = k0; k < k1; ++k) {
        float w = W[k * 64 + n];
        float s = 1.0f, o = 0.0f;
        if (g) {
            s = g[k] * __frsqrt_rn(v[k] + 1e-3f);
            o = b[k] - mu[k] * s;
        }
        int idx = ((nt * nkc + (k >> 5)) * 64 + ((k >> 3) & 3) * 16 + lrow) * 8 + (k & 7);
        Wf[idx] = (bf16_t)(w * s);
        acc += o * w;
    }
    part[kc * 64 + n] = acc;
    __syncthreads();
    if (kc == 0) cb[n] = c[n] + part[n] + part[64 + n] + part[128 + n] + part[192 + n];
}

__global__ void fold_kernel(
    const float* mg1, const float* mb1, const float* mmu1, const float* mv1,
    const float* mW1, const float* mc1,
    const float* mg2, const float* mb2, const float* mmu2, const float* mv2,
    const float* mW2, const float* mc2,
    const float* eW1, const float* ec1, const float* eW2, const float* ec2,
    const float* ug1, const float* ub1, const float* umu1, const float* uv1,
    const float* uW1, const float* uc1,
    const float* ug2, const float* ub2, const float* umu2, const float* uv2,
    const float* uW2, const float* uc2,
    bf16_t* wcat, bf16_t* uW1f, bf16_t* uW2f,
    float* cm1, float* cm2, float* ce1, float* ce2, float* cu1, float* cu2)
{
    __shared__ float part[256];
    int t = threadIdx.x;
    switch (blockIdx.x) {
        case 0: fold_frag(64,  mW1, mg1, mb1, mmu1, mv1, mc1, wcat,         cm1, t, part); break;
        case 1: fold_frag(64,  mW2, mg2, mb2, mmu2, mv2, mc2, wcat + 4096,  cm2, t, part); break;
        case 2: fold_frag(64,  eW1, nullptr, nullptr, nullptr, nullptr, ec1, wcat + 8192,  ce1, t, part); break;
        case 3: fold_frag(64,  eW2, nullptr, nullptr, nullptr, nullptr, ec2, wcat + 12288, ce2, t, part); break;
        case 4: fold_frag(128, uW1, ug1, ub1, umu1, uv1, uc1, uW1f, cu1, t, part); break;
        case 5: fold_frag(64,  uW2, ug2, ub2, umu2, uv2, uc2, uW2f, cu2, t, part); break;
    }
}

// ---------------- CSR build ----------------
__global__ void hist_kernel(const int* __restrict__ src, int* __restrict__ cnt) {
    int e = blockIdx.x * 256 + threadIdx.x;
    if (e < NE) atomicAdd(&cnt[src[e]], 1);
}

__global__ void scanA_kernel(const int* __restrict__ cnt, int* __restrict__ part,
                             int* __restrict__ btot) {
    __shared__ int s[256];
    int tid = threadIdx.x;
    int i = blockIdx.x * 256 + tid;
    int v = (i < NN) ? cnt[i] : 0;
    s[tid] = v;
    __syncthreads();
    #pragma unroll
    for (int off = 1; off < 256; off <<= 1) {
        int t = (tid >= off) ? s[tid - off] : 0;
        __syncthreads();
        s[tid] += t;
        __syncthreads();
    }
    if (i < NN) part[i] = s[tid] - v;            // exclusive within block
    if (tid == 255) btot[blockIdx.x] = s[255];   // block total
}

__global__ void scanB_kernel(int* __restrict__ btot, int nblk) {
    __shared__ int s[256];
    int tid = threadIdx.x;
    int v = (tid < nblk) ? btot[tid] : 0;
    s[tid] = v;
    __syncthreads();
    #pragma unroll
    for (int off = 1; off < 256; off <<= 1) {
        int t = (tid >= off) ? s[tid - off] : 0;
        __syncthreads();
        s[tid] += t;
        __syncthreads();
    }
    if (tid < nblk) btot[tid] = s[tid] - v;      // exclusive block bases
}

__global__ void scanC_kernel(const int* __restrict__ part, const int* __restrict__ btot,
                             int* __restrict__ woff) {
    int i = blockIdx.x * 256 + threadIdx.x;
    if (i < NN) woff[i] = part[i] + btot[i >> 8];
}

__global__ void fill_kernel(const int* __restrict__ src, int* __restrict__ woff,
                            int* __restrict__ elist) {
    int e = blockIdx.x * 256 + threadIdx.x;
    if (e < NE) {
        int pos = atomicAdd(&woff[src[e]], 1);
        elist[pos] = e;
    }
}

// ---------------- edge helpers ----------------
__device__ __forceinline__ void mk_frag_hilo(const float* row, int quad,
        bf16x8& hi0, bf16x8& lo0, bf16x8& hi1, bf16x8& lo1)
{
    #pragma unroll
    for (int j = 0; j < 8; ++j) {
        float x0 = row[quad * 8 + j];
        float x1 = row[32 + quad * 8 + j];
        bf16_t h0 = (bf16_t)x0, h1 = (bf16_t)x1;
        hi0[j] = h0; lo0[j] = (bf16_t)(x0 - (float)h0);
        hi1[j] = h1; lo1[j] = (bf16_t)(x1 - (float)h1);
    }
}

__device__ __forceinline__ bf16x8 ldb(const bf16_t* wf, int slot, int lane) {
    return *(const bf16x8*)(wf + (slot * 64 + lane) * 8);
}

__device__ __forceinline__ void gemm64_hilo(const bf16_t* wf, int m,
        bf16x8 h0, bf16x8 l0, bf16x8 h1, bf16x8 l1, f32x4 (&acc)[4], int lane)
{
    #pragma unroll
    for (int nt = 0; nt < 4; ++nt) {
        bf16x8 b0 = ldb(wf, m * 8 + nt * 2 + 0, lane);
        bf16x8 b1 = ldb(wf, m * 8 + nt * 2 + 1, lane);
        f32x4 c = {0.f, 0.f, 0.f, 0.f};
        c = __builtin_amdgcn_mfma_f32_16x16x32_bf16(h0, b0, c, 0, 0, 0);
        c = __builtin_amdgcn_mfma_f32_16x16x32_bf16(l0, b0, c, 0, 0, 0);
        c = __builtin_amdgcn_mfma_f32_16x16x32_bf16(h1, b1, c, 0, 0, 0);
        c = __builtin_amdgcn_mfma_f32_16x16x32_bf16(l1, b1, c, 0, 0, 0);
        acc[nt] = c;
    }
}

__device__ __forceinline__ void gemm64(const bf16_t* wf, int m,
        bf16x8 a0, bf16x8 a1, f32x4 (&acc)[4], int lane)
{
    #pragma unroll
    for (int nt = 0; nt < 4; ++nt) {
        bf16x8 b0 = ldb(wf, m * 8 + nt * 2 + 0, lane);
        bf16x8 b1 = ldb(wf, m * 8 + nt * 2 + 1, lane);
        f32x4 c = {0.f, 0.f, 0.f, 0.f};
        c = __builtin_amdgcn_mfma_f32_16x16x32_bf16(a0, b0, c, 0, 0, 0);
        c = __builtin_amdgcn_mfma_f32_16x16x32_bf16(a1, b1, c, 0, 0, 0);
        acc[nt] = c;
    }
}

// gelu -> per-wave A-fragment-order buffer
__device__ __forceinline__ void epi_to_frag(const f32x4 (&acc)[4], const float* bias,
        bf16_t* h, int lrow, int quad)
{
    #pragma unroll
    for (int nt = 0; nt < 4; ++nt) {
        float bb = bias[nt * 16 + lrow];
        #pragma unroll
        for (int r = 0; r < 4; ++r)
            h[((nt * 2 + (lrow >> 3)) * 16 + quad * 4 + r) * 8 + (lrow & 7)] =
                (bf16_t)gelu_f(acc[nt][r] + bb);
    }
}

// ---------------- edge kernel ----------------
__global__ __launch_bounds__(256) void edge_kernel(
    const float* __restrict__ node_feats, const float* __restrict__ edge_feats,
    const int* __restrict__ src, const int* __restrict__ dst,
    const bf16_t* __restrict__ wcat,
    const float* __restrict__ cm1, const float* __restrict__ cm2,
    const float* __restrict__ ce1, const float* __restrict__ ce2,
    float* __restrict__ s_acc, bf16_t* __restrict__ buf, int use_csr)
{
    __shared__ bf16_t wf[16384];
    __shared__ bf16_t hf[4][1024];

    const int tid  = threadIdx.x;
    const int wave = tid >> 6;
    const int lane = tid & 63;
    const int quad = lane >> 4;
    const int lrow = lane & 15;

    #pragma unroll
    for (int i = 0; i < 8; ++i) {
        int chunk = tid + i * 256;
        *(bf16x8*)(wf + chunk * 8) = *(const bf16x8*)(wcat + chunk * 8);
    }
    __syncthreads();

    const int ebase = blockIdx.x * 64 + wave * 16;
    bf16_t* h = hf[wave];

    f32x4 acc[4];

    // ---- edge-transformer path ----
    {
        const float* erow = edge_feats + (size_t)(ebase + lrow) * 64;
        bf16x8 h0, l0, h1, l1;
        mk_frag_hilo(erow, quad, h0, l0, h1, l1);
        gemm64_hilo(wf, 2, h0, l0, h1, l1, acc, lane);
        epi_to_frag(acc, ce1, h, lrow, quad);
    }
    float er[4][4];
    {
        bf16x8 a0 = *(const bf16x8*)(h + lane * 8);
        bf16x8 a1 = *(const bf16x8*)(h + (lane + 64) * 8);
        gemm64(wf, 3, a0, a1, acc, lane);
        #pragma unroll
        for (int nt = 0; nt < 4; ++nt) {
            float bb = ce2[nt * 16 + lrow];
            #pragma unroll
            for (int r = 0; r < 4; ++r) er[nt][r] = gelu_f(acc[nt][r] + bb);
        }
    }

    // ---- message path ----
    {
        const int dnode = dst[ebase + lrow];
        const float* nrow = node_feats + (size_t)dnode * 64;
        bf16x8 h0, l0, h1, l1;
        mk_frag_hilo(nrow, quad, h0, l0, h1, l1);
        gemm64_hilo(wf, 0, h0, l0, h1, l1, acc, lane);
        epi_to_frag(acc, cm1, h, lrow, quad);
    }
    float msg[4][4];
    {
        bf16x8 a0 = *(const bf16x8*)(h + lane * 8);
        bf16x8 a1 = *(const bf16x8*)(h + (lane + 64) * 8);
        gemm64(wf, 1, a0, a1, acc, lane);
        #pragma unroll
        for (int nt = 0; nt < 4; ++nt) {
            float bb = cm2[nt * 16 + lrow];
            #pragma unroll
            for (int r = 0; r < 4; ++r) msg[nt][r] = gelu_f(acc[nt][r] + bb);
        }
    }

    // ---- gated output (C layout: row=quad*4+r, col=nt*16+lrow) ----
    if (use_csr) {
        #pragma unroll
        for (int r = 0; r < 4; ++r) {
            bf16_t* bp = buf + (size_t)(ebase + quad * 4 + r) * 64;
            #pragma unroll
            for (int nt = 0; nt < 4; ++nt)
                bp[nt * 16 + lrow] = (bf16_t)(msg[nt][r] * er[nt][r]);
        }
    } else {
        #pragma unroll
        for (int r = 0; r < 4; ++r) {
            float* srow = s_acc + (size_t)src[ebase + quad * 4 + r] * 64;
            #pragma unroll
            for (int nt = 0; nt < 4; ++nt)
                unsafeAtomicAdd(srow + nt * 16 + lrow, msg[nt][r] * er[nt][r]);
        }
    }
}

// ---------------- aggregation: wave per node, fp32 sum, mean ----------------
__global__ __launch_bounds__(256) void agg_kernel(
    const bf16_t* __restrict__ buf, const int* __restrict__ elist,
    const int* __restrict__ woff, const int* __restrict__ cnt,
    float* __restrict__ agg)
{
    const int wave = threadIdx.x >> 6;
    const int lane = threadIdx.x & 63;
    const int n = blockIdx.x * 4 + wave;
    const int deg = cnt[n];
    const int end = woff[n];            // after fill, woff = start + cnt
    const int start = end - deg;

    float s0 = 0.f, s1 = 0.f, s2 = 0.f, s3 = 0.f;
    int j = start;
    for (; j + 4 <= end; j += 4) {
        int e0 = elist[j], e1 = elist[j + 1], e2 = elist[j + 2], e3 = elist[j + 3];
        s0 += (float)buf[(size_t)e0 * 64 + lane];
        s1 += (float)buf[(size_t)e1 * 64 + lane];
        s2 += (float)buf[(size_t)e2 * 64 + lane];
        s3 += (float)buf[(size_t)e3 * 64 + lane];
    }
    for (; j < end; ++j)
        s0 += (float)buf[(size_t)elist[j] * 64 + lane];

    float r = (deg > 0) ? (s0 + s1 + s2 + s3) * __builtin_amdgcn_rcpf((float)deg) : 0.f;
    agg[(size_t)n * 64 + lane] = r;
}

// ---------------- update MLP ----------------
__global__ __launch_bounds__(256) void update_kernel(
    const float* __restrict__ node_feats,
    const float* __restrict__ aggv, const int* __restrict__ cnt,   // cnt!=null -> divide
    const bf16_t* __restrict__ uW1f, const float* __restrict__ cu1,
    const bf16_t* __restrict__ uW2f, const float* __restrict__ cu2,
    float* __restrict__ out)
{
    __shared__ bf16_t w1f[8192];
    __shared__ bf16_t w2f[4096];
    __shared__ bf16_t hf[4][1024];

    const int tid  = threadIdx.x;
    const int wave = tid >> 6;
    const int lane = tid & 63;
    const int quad = lane >> 4;
    const int lrow = lane & 15;

    #pragma unroll
    for (int i = 0; i < 4; ++i) {
        int chunk = tid + i * 256;
        *(bf16x8*)(w1f + chunk * 8) = *(const bf16x8*)(uW1f + chunk * 8);
    }
    #pragma unroll
    for (int i = 0; i < 2; ++i) {
        int chunk = tid + i * 256;
        *(bf16x8*)(w2f + chunk * 8) = *(const bf16x8*)(uW2f + chunk * 8);
    }
    __syncthreads();

    const int nbase = blockIdx.x * 64 + wave * 16;
    int arow = nbase + lrow;
    arow = arow < NN ? arow : NN - 1;   // clamp gather; stores predicated below

    const float* nf   = node_feats + (size_t)arow * 64;
    const float* srow = aggv + (size_t)arow * 64;
    float inv = cnt ? 1.0f / fmaxf((float)cnt[arow], 1.0f) : 1.0f;

    bf16x8 ah[4], al[4];
    #pragma unroll
    for (int j = 0; j < 8; ++j) {
        float x0 = nf[quad * 8 + j];
        float x1 = nf[32 + quad * 8 + j];
        float x2 = srow[quad * 8 + j] * inv;
        float x3 = srow[32 + quad * 8 + j] * inv;
        bf16_t h0 = (bf16_t)x0, h1 = (bf16_t)x1, h2 = (bf16_t)x2, h3 = (bf16_t)x3;
        ah[0][j] = h0; al[0][j] = (bf16_t)(x0 - (float)h0);
        ah[1][j] = h1; al[1][j] = (bf16_t)(x1 - (float)h1);
        ah[2][j] = h2; al[2][j] = (bf16_t)(x2 - (float)h2);
        ah[3][j] = h3; al[3][j] = (bf16_t)(x3 - (float)h3);
    }

    f32x4 acc[4];
    #pragma unroll
    for (int nt = 0; nt < 4; ++nt) {
        f32x4 c = {0.f, 0.f, 0.f, 0.f};
        #pragma unroll
        for (int kk = 0; kk < 4; ++kk) {
            bf16x8 b = *(const bf16x8*)(w1f + ((nt * 4 + kk) * 64 + lane) * 8);
            c = __builtin_amdgcn_mfma_f32_16x16x32_bf16(ah[kk], b, c, 0, 0, 0);
            c = __builtin_amdgcn_mfma_f32_16x16x32_bf16(al[kk], b, c, 0, 0, 0);
        }
        acc[nt] = c;
    }
    bf16_t* hb = hf[wave];
    epi_to_frag(acc, cu1, hb, lrow, quad);

    bf16x8 ha0 = *(const bf16x8*)(hb + lane * 8);
    bf16x8 ha1 = *(const bf16x8*)(hb + (lane + 64) * 8);
    gemm64(w2f, 0, ha0, ha1, acc, lane);

    #pragma unroll
    for (int nt = 0; nt < 4; ++nt) {
        int col = nt * 16 + lrow;
        float bb = cu2[col];
        #pragma unroll
        for (int r = 0; r < 4; ++r) {
            int row = nbase + quad * 4 + r;
            if (row < NN)
                out[(size_t)row * 64 + col] = gelu_f(acc[nt][r] + bb);
        }
    }
}

// ---------------- launch ----------------
extern "C" void kernel_launch(void* const* d_in, const int* in_sizes, int n_in,
                              void* d_out, int out_size, void* d_ws, size_t ws_size,
                              hipStream_t stream) {
    const float* node_feats = (const float*)d_in[0];
    const float* edge_feats = (const float*)d_in[1];
    const int*   src        = (const int*)d_in[2];
    const int*   dst        = (const int*)d_in[3];

    char* ws = (char*)d_ws;
    const bool csr = ws_size >= (size_t)119200000;

    size_t off = 0;
    bf16_t* buf = nullptr; float* agg = nullptr; int* elist = nullptr;
    int* cnt = nullptr; int* woff = nullptr; int* part = nullptr; int* btot = nullptr;
    float* s_acc = nullptr;

    if (csr) {
        buf   = (bf16_t*)(ws + off); off += (size_t)NE * 64 * 2;   // 102,400,000
        agg   = (float*)(ws + off);  off += (size_t)NN * 64 * 4;   //  12,800,000
        elist = (int*)(ws + off);    off += (size_t)NE * 4;        //   3,200,000
        cnt   = (int*)(ws + off);    off += (size_t)NN * 4;
        woff  = (int*)(ws + off);    off += (size_t)NN * 4;
        part  = (int*)(ws + off);    off += (size_t)NN * 4;
        btot  = (int*)(ws + off);    off += 1024;
    } else {
        s_acc = (float*)(ws + off);  off += (size_t)NN * 64 * 4;   // 12,800,000
        cnt   = (int*)(ws + off);    off += (size_t)NN * 4;
    }
    bf16_t* wcat = (bf16_t*)(ws + off); off += 32768;
    bf16_t* uW1f = (bf16_t*)(ws + off); off += 16384;
    bf16_t* uW2f = (bf16_t*)(ws + off); off += 8192;
    float* cm1 = (float*)(ws + off); off += 256;
    float* cm2 = (float*)(ws + off); off += 256;
    float* ce1 = (float*)(ws + off); off += 256;
    float* ce2 = (float*)(ws + off); off += 256;
    float* cu1 = (float*)(ws + off); off += 256;
    float* cu2 = (float*)(ws + off); off += 256;

    if (csr) {
        hipMemsetAsync(cnt, 0, (size_t)NN * 4, stream);
    } else {
        hipMemsetAsync(s_acc, 0, (size_t)NN * 64 * 4 + (size_t)NN * 4, stream);
    }

    fold_kernel<<<6, 256, 0, stream>>>(
        (const float*)d_in[4],  (const float*)d_in[5],  (const float*)d_in[6],  (const float*)d_in[7],
        (const float*)d_in[8],  (const float*)d_in[9],
        (const float*)d_in[10], (const float*)d_in[11], (const float*)d_in[12], (const float*)d_in[13],
        (const float*)d_in[14], (const float*)d_in[15],
        (const float*)d_in[16], (const float*)d_in[17], (const float*)d_in[18], (const float*)d_in[19],
        (const float*)d_in[20], (const float*)d_in[21], (const float*)d_in[22], (const float*)d_in[23],
        (const float*)d_in[24], (const float*)d_in[25],
        (const float*)d_in[26], (const float*)d_in[27], (const float*)d_in[28], (const float*)d_in[29],
        (const float*)d_in[30], (const float*)d_in[31],
        wcat, uW1f, uW2f, cm1, cm2, ce1, ce2, cu1, cu2);

    hist_kernel<<<(NE + 255) / 256, 256, 0, stream>>>(src, cnt);

    if (csr) {
        const int NBLK = (NN + 255) / 256;   // 196
        scanA_kernel<<<NBLK, 256, 0, stream>>>(cnt, part, btot);
        scanB_kernel<<<1, 256, 0, stream>>>(btot, NBLK);
        scanC_kernel<<<NBLK, 256, 0, stream>>>(part, btot, woff);
        fill_kernel<<<(NE + 255) / 256, 256, 0, stream>>>(src, woff, elist);
    }

    edge_kernel<<<NE / 64, 256, 0, stream>>>(
        node_feats, edge_feats, src, dst,
        wcat, cm1, cm2, ce1, ce2, s_acc, buf, csr ? 1 : 0);

    if (csr) {
        agg_kernel<<<NN / 4, 256, 0, stream>>>(buf, elist, woff, cnt, agg);
        update_kernel<<<(NN + 63) / 64, 256, 0, stream>>>(
            node_feats, agg, nullptr, uW1f, cu1, uW2f, cu2, (float*)d_out);
    } else {
        update_kernel<<<(NN + 63) / 64, 256, 0, stream>>>(
            node_feats, s_acc, cnt, uW1f, cu1, uW2f, cu2, (float*)d_out);
    }
}

// Round 5
// 519.522 us; speedup vs baseline: 1.0846x; 1.0846x over previous
//
#include <hip/hip_runtime.h>
#include <hip/hip_bf16.h>

#define NN 50000
#define NE 800000

typedef __bf16 bf16_t;
typedef bf16_t bf16x8 __attribute__((ext_vector_type(8)));
typedef float f32x4 __attribute__((ext_vector_type(4)));

// fast gelu: x * sigmoid(1.595769x + 0.0713548x^3), max abs err vs erf-gelu ~4e-4
__device__ __forceinline__ float gelu_f(float x) {
    float v = x * fmaf(x * x, 0.07135481627f, 1.595769122f);
    float e = __expf(-v);
    return x * __builtin_amdgcn_rcpf(1.0f + e);
}

// ---------------- weight folding into MFMA B-fragment order ----------------
// idx = ((nt*nkc + (k>>5))*64 + ((k>>3)&3)*16 + lrow)*8 + (k&7), n = nt*16+lrow
__device__ void fold_frag(int K, const float* W, const float* g, const float* b,
                          const float* mu, const float* v, const float* c,
                          bf16_t* Wf, float* cb, int tid, float* part) {
    const int n = tid & 63, kc = tid >> 6;
    const int nt = n >> 4, lrow = n & 15, nkc = K >> 5;
    const int kq = K >> 2, k0 = kc * kq, k1 = k0 + kq;
    float acc = 0.f;
    for (int k = k0; k < k1; ++k) {
        float w = W[k * 64 + n];
        float s = 1.0f, o = 0.0f;
        if (g) {
            s = g[k] * __frsqrt_rn(v[k] + 1e-3f);
            o = b[k] - mu[k] * s;
        }
        int idx = ((nt * nkc + (k >> 5)) * 64 + ((k >> 3) & 3) * 16 + lrow) * 8 + (k & 7);
        Wf[idx] = (bf16_t)(w * s);
        acc += o * w;
    }
    part[kc * 64 + n] = acc;
    __syncthreads();
    if (kc == 0) cb[n] = c[n] + part[n] + part[64 + n] + part[128 + n] + part[192 + n];
}

__global__ void fold_kernel(
    const float* mg1, const float* mb1, const float* mmu1, const float* mv1,
    const float* mW1, const float* mc1,
    const float* mg2, const float* mb2, const float* mmu2, const float* mv2,
    const float* mW2, const float* mc2,
    const float* eW1, const float* ec1, const float* eW2, const float* ec2,
    const float* ug1, const float* ub1, const float* umu1, const float* uv1,
    const float* uW1, const float* uc1,
    const float* ug2, const float* ub2, const float* umu2, const float* uv2,
    const float* uW2, const float* uc2,
    bf16_t* wcat, bf16_t* uW1f, bf16_t* uW2f,
    float* cm1, float* cm2, float* ce1, float* ce2, float* cu1, float* cu2)
{
    __shared__ float part[256];
    int t = threadIdx.x;
    switch (blockIdx.x) {
        case 0: fold_frag(64,  mW1, mg1, mb1, mmu1, mv1, mc1, wcat,         cm1, t, part); break;
        case 1: fold_frag(64,  mW2, mg2, mb2, mmu2, mv2, mc2, wcat + 4096,  cm2, t, part); break;
        case 2: fold_frag(64,  eW1, nullptr, nullptr, nullptr, nullptr, ec1, wcat + 8192,  ce1, t, part); break;
        case 3: fold_frag(64,  eW2, nullptr, nullptr, nullptr, nullptr, ec2, wcat + 12288, ce2, t, part); break;
        case 4: fold_frag(128, uW1, ug1, ub1, umu1, uv1, uc1, uW1f, cu1, t, part); break;
        case 5: fold_frag(64,  uW2, ug2, ub2, umu2, uv2, uc2, uW2f, cu2, t, part); break;
    }
}

// ---------------- CSR build ----------------
__global__ void hist_kernel(const int* __restrict__ src, int* __restrict__ cnt) {
    int e = blockIdx.x * 256 + threadIdx.x;
    if (e < NE) atomicAdd(&cnt[src[e]], 1);
}

__global__ void scanA_kernel(const int* __restrict__ cnt, int* __restrict__ part,
                             int* __restrict__ btot) {
    __shared__ int s[256];
    int tid = threadIdx.x;
    int i = blockIdx.x * 256 + tid;
    int v = (i < NN) ? cnt[i] : 0;
    s[tid] = v;
    __syncthreads();
    #pragma unroll
    for (int off = 1; off < 256; off <<= 1) {
        int t = (tid >= off) ? s[tid - off] : 0;
        __syncthreads();
        s[tid] += t;
        __syncthreads();
    }
    if (i < NN) part[i] = s[tid] - v;
    if (tid == 255) btot[blockIdx.x] = s[255];
}

__global__ void scanB_kernel(int* __restrict__ btot, int nblk) {
    __shared__ int s[256];
    int tid = threadIdx.x;
    int v = (tid < nblk) ? btot[tid] : 0;
    s[tid] = v;
    __syncthreads();
    #pragma unroll
    for (int off = 1; off < 256; off <<= 1) {
        int t = (tid >= off) ? s[tid - off] : 0;
        __syncthreads();
        s[tid] += t;
        __syncthreads();
    }
    if (tid < nblk) btot[tid] = s[tid] - v;
}

__global__ void scanC_kernel(const int* __restrict__ part, const int* __restrict__ btot,
                             int* __restrict__ woff) {
    int i = blockIdx.x * 256 + threadIdx.x;
    if (i < NN) woff[i] = part[i] + btot[i >> 8];
}

// writes CSR position per edge (inverse permutation)
__global__ void fill_kernel(const int* __restrict__ src, int* __restrict__ woff,
                            int* __restrict__ pos) {
    int e = blockIdx.x * 256 + threadIdx.x;
    if (e < NE) pos[e] = atomicAdd(&woff[src[e]], 1);
}

// ---------------- MFMA helpers ----------------
__device__ __forceinline__ void mk_frag_hilo(const float* row, int quad,
        bf16x8& hi0, bf16x8& lo0, bf16x8& hi1, bf16x8& lo1)
{
    #pragma unroll
    for (int j = 0; j < 8; ++j) {
        float x0 = row[quad * 8 + j];
        float x1 = row[32 + quad * 8 + j];
        bf16_t h0 = (bf16_t)x0, h1 = (bf16_t)x1;
        hi0[j] = h0; lo0[j] = (bf16_t)(x0 - (float)h0);
        hi1[j] = h1; lo1[j] = (bf16_t)(x1 - (float)h1);
    }
}

__device__ __forceinline__ bf16x8 ldb(const bf16_t* wf, int slot, int lane) {
    return *(const bf16x8*)(wf + (slot * 64 + lane) * 8);
}

__device__ __forceinline__ void gemm64_hilo(const bf16_t* wf, int m,
        bf16x8 h0, bf16x8 l0, bf16x8 h1, bf16x8 l1, f32x4 (&acc)[4], int lane)
{
    #pragma unroll
    for (int nt = 0; nt < 4; ++nt) {
        bf16x8 b0 = ldb(wf, m * 8 + nt * 2 + 0, lane);
        bf16x8 b1 = ldb(wf, m * 8 + nt * 2 + 1, lane);
        f32x4 c = {0.f, 0.f, 0.f, 0.f};
        c = __builtin_amdgcn_mfma_f32_16x16x32_bf16(h0, b0, c, 0, 0, 0);
        c = __builtin_amdgcn_mfma_f32_16x16x32_bf16(l0, b0, c, 0, 0, 0);
        c = __builtin_amdgcn_mfma_f32_16x16x32_bf16(h1, b1, c, 0, 0, 0);
        c = __builtin_amdgcn_mfma_f32_16x16x32_bf16(l1, b1, c, 0, 0, 0);
        acc[nt] = c;
    }
}

__device__ __forceinline__ void gemm64(const bf16_t* wf, int m,
        bf16x8 a0, bf16x8 a1, f32x4 (&acc)[4], int lane)
{
    #pragma unroll
    for (int nt = 0; nt < 4; ++nt) {
        bf16x8 b0 = ldb(wf, m * 8 + nt * 2 + 0, lane);
        bf16x8 b1 = ldb(wf, m * 8 + nt * 2 + 1, lane);
        f32x4 c = {0.f, 0.f, 0.f, 0.f};
        c = __builtin_amdgcn_mfma_f32_16x16x32_bf16(a0, b0, c, 0, 0, 0);
        c = __builtin_amdgcn_mfma_f32_16x16x32_bf16(a1, b1, c, 0, 0, 0);
        acc[nt] = c;
    }
}

// gelu -> per-wave A-fragment-order buffer
__device__ __forceinline__ void epi_to_frag(const f32x4 (&acc)[4], const float* bias,
        bf16_t* h, int lrow, int quad)
{
    #pragma unroll
    for (int nt = 0; nt < 4; ++nt) {
        float bb = bias[nt * 16 + lrow];
        #pragma unroll
        for (int r = 0; r < 4; ++r)
            h[((nt * 2 + (lrow >> 3)) * 16 + quad * 4 + r) * 8 + (lrow & 7)] =
                (bf16_t)gelu_f(acc[nt][r] + bb);
    }
}

// ---------------- per-node message MLP (the 16x redundancy fix) ----------------
__global__ __launch_bounds__(256) void node_msg_kernel(
    const float* __restrict__ node_feats, const bf16_t* __restrict__ wcat,
    const float* __restrict__ cm1, const float* __restrict__ cm2,
    bf16_t* __restrict__ msg)
{
    __shared__ bf16_t wf[8192];      // mW1f, mW2f (16 KB)
    __shared__ bf16_t hf[4][1024];

    const int tid  = threadIdx.x;
    const int wave = tid >> 6;
    const int lane = tid & 63;
    const int quad = lane >> 4;
    const int lrow = lane & 15;

    #pragma unroll
    for (int i = 0; i < 4; ++i) {
        int chunk = tid + i * 256;
        *(bf16x8*)(wf + chunk * 8) = *(const bf16x8*)(wcat + chunk * 8);
    }
    __syncthreads();

    const int nbase = blockIdx.x * 64 + wave * 16;
    int arow = nbase + lrow;
    arow = arow < NN ? arow : NN - 1;

    f32x4 acc[4];
    {
        const float* nrow = node_feats + (size_t)arow * 64;
        bf16x8 h0, l0, h1, l1;
        mk_frag_hilo(nrow, quad, h0, l0, h1, l1);
        gemm64_hilo(wf, 0, h0, l0, h1, l1, acc, lane);
        epi_to_frag(acc, cm1, hf[wave], lrow, quad);
    }
    bf16x8 a0 = *(const bf16x8*)(hf[wave] + lane * 8);
    bf16x8 a1 = *(const bf16x8*)(hf[wave] + (lane + 64) * 8);
    gemm64(wf, 1, a0, a1, acc, lane);

    #pragma unroll
    for (int nt = 0; nt < 4; ++nt) {
        float bb = cm2[nt * 16 + lrow];
        #pragma unroll
        for (int r = 0; r < 4; ++r) {
            int row = nbase + quad * 4 + r;
            if (row < NN)
                msg[(size_t)row * 64 + nt * 16 + lrow] = (bf16_t)gelu_f(acc[nt][r] + bb);
        }
    }
}

// ---------------- edge kernel: er MLP + gather msg + gate + CSR-permuted store ----------------
__global__ __launch_bounds__(256) void edge_kernel(
    const float* __restrict__ edge_feats,
    const int* __restrict__ src, const int* __restrict__ dst,
    const int* __restrict__ pos,
    const bf16_t* __restrict__ wcat,
    const float* __restrict__ ce1, const float* __restrict__ ce2,
    const bf16_t* __restrict__ msg,
    float* __restrict__ s_acc, bf16_t* __restrict__ buf, int use_csr)
{
    __shared__ bf16_t wf[8192];      // eW1f, eW2f (16 KB)
    __shared__ bf16_t hf[4][1024];

    const int tid  = threadIdx.x;
    const int wave = tid >> 6;
    const int lane = tid & 63;
    const int quad = lane >> 4;
    const int lrow = lane & 15;

    #pragma unroll
    for (int i = 0; i < 4; ++i) {
        int chunk = tid + i * 256;
        *(bf16x8*)(wf + chunk * 8) = *(const bf16x8*)(wcat + 8192 + chunk * 8);
    }
    __syncthreads();

    const int ebase = blockIdx.x * 64 + wave * 16;
    bf16_t* h = hf[wave];

    // issue gathers early: msg rows for this lane's 4 C-rows (edges ebase+quad*4+r)
    int erow_id[4];
    #pragma unroll
    for (int r = 0; r < 4; ++r) erow_id[r] = ebase + quad * 4 + r;
    bf16_t mg[4][4];
    #pragma unroll
    for (int r = 0; r < 4; ++r) {
        const bf16_t* mrow = msg + (size_t)dst[erow_id[r]] * 64;
        #pragma unroll
        for (int nt = 0; nt < 4; ++nt) mg[r][nt] = mrow[nt * 16 + lrow];
    }

    // er MLP
    f32x4 acc[4];
    {
        const float* efr = edge_feats + (size_t)(ebase + lrow) * 64;
        bf16x8 h0, l0, h1, l1;
        mk_frag_hilo(efr, quad, h0, l0, h1, l1);
        gemm64_hilo(wf, 0, h0, l0, h1, l1, acc, lane);
        epi_to_frag(acc, ce1, h, lrow, quad);
    }
    bf16x8 a0 = *(const bf16x8*)(h + lane * 8);
    bf16x8 a1 = *(const bf16x8*)(h + (lane + 64) * 8);
    gemm64(wf, 1, a0, a1, acc, lane);

    // gate + output (C layout: row=quad*4+r, col=nt*16+lrow)
    if (use_csr) {
        int pe[4];
        #pragma unroll
        for (int r = 0; r < 4; ++r) pe[r] = pos[erow_id[r]];
        #pragma unroll
        for (int nt = 0; nt < 4; ++nt) {
            float bb = ce2[nt * 16 + lrow];
            #pragma unroll
            for (int r = 0; r < 4; ++r) {
                float er = gelu_f(acc[nt][r] + bb);
                buf[(size_t)pe[r] * 64 + nt * 16 + lrow] = (bf16_t)(er * (float)mg[r][nt]);
            }
        }
    } else {
        #pragma unroll
        for (int nt = 0; nt < 4; ++nt) {
            float bb = ce2[nt * 16 + lrow];
            #pragma unroll
            for (int r = 0; r < 4; ++r) {
                float er = gelu_f(acc[nt][r] + bb);
                unsafeAtomicAdd(&s_acc[(size_t)src[erow_id[r]] * 64 + nt * 16 + lrow],
                                er * (float)mg[r][nt]);
            }
        }
    }
}

// ---------------- aggregation: contiguous CSR segments, streaming ----------------
__global__ __launch_bounds__(256) void agg_kernel(
    const bf16_t* __restrict__ buf, const int* __restrict__ woff,
    const int* __restrict__ cnt, float* __restrict__ agg)
{
    const int wave = threadIdx.x >> 6;
    const int lane = threadIdx.x & 63;
    const int n = blockIdx.x * 4 + wave;
    const int deg = cnt[n];
    const int end = woff[n];            // after fill, woff = start + cnt
    const int start = end - deg;

    float s0 = 0.f, s1 = 0.f, s2 = 0.f, s3 = 0.f;
    const bf16_t* p = buf + (size_t)start * 64 + lane;
    int j = start;
    for (; j + 4 <= end; j += 4) {
        s0 += (float)p[0];
        s1 += (float)p[64];
        s2 += (float)p[128];
        s3 += (float)p[192];
        p += 256;
    }
    for (; j < end; ++j) { s0 += (float)p[0]; p += 64; }

    float r = (deg > 0) ? (s0 + s1 + s2 + s3) * __builtin_amdgcn_rcpf((float)deg) : 0.f;
    agg[(size_t)n * 64 + lane] = r;
}

// ---------------- update MLP ----------------
__global__ __launch_bounds__(256) void update_kernel(
    const float* __restrict__ node_feats,
    const float* __restrict__ aggv, const int* __restrict__ cnt,   // cnt!=null -> divide
    const bf16_t* __restrict__ uW1f, const float* __restrict__ cu1,
    const bf16_t* __restrict__ uW2f, const float* __restrict__ cu2,
    float* __restrict__ out)
{
    __shared__ bf16_t w1f[8192];
    __shared__ bf16_t w2f[4096];
    __shared__ bf16_t hf[4][1024];

    const int tid  = threadIdx.x;
    const int wave = tid >> 6;
    const int lane = tid & 63;
    const int quad = lane >> 4;
    const int lrow = lane & 15;

    #pragma unroll
    for (int i = 0; i < 4; ++i) {
        int chunk = tid + i * 256;
        *(bf16x8*)(w1f + chunk * 8) = *(const bf16x8*)(uW1f + chunk * 8);
    }
    #pragma unroll
    for (int i = 0; i < 2; ++i) {
        int chunk = tid + i * 256;
        *(bf16x8*)(w2f + chunk * 8) = *(const bf16x8*)(uW2f + chunk * 8);
    }
    __syncthreads();

    const int nbase = blockIdx.x * 64 + wave * 16;
    int arow = nbase + lrow;
    arow = arow < NN ? arow : NN - 1;

    const float* nf   = node_feats + (size_t)arow * 64;
    const float* srow = aggv + (size_t)arow * 64;
    float inv = cnt ? 1.0f / fmaxf((float)cnt[arow], 1.0f) : 1.0f;

    bf16x8 ah[4], al[4];
    #pragma unroll
    for (int j = 0; j < 8; ++j) {
        float x0 = nf[quad * 8 + j];
        float x1 = nf[32 + quad * 8 + j];
        float x2 = srow[quad * 8 + j] * inv;
        float x3 = srow[32 + quad * 8 + j] * inv;
        bf16_t h0 = (bf16_t)x0, h1 = (bf16_t)x1, h2 = (bf16_t)x2, h3 = (bf16_t)x3;
        ah[0][j] = h0; al[0][j] = (bf16_t)(x0 - (float)h0);
        ah[1][j] = h1; al[1][j] = (bf16_t)(x1 - (float)h1);
        ah[2][j] = h2; al[2][j] = (bf16_t)(x2 - (float)h2);
        ah[3][j] = h3; al[3][j] = (bf16_t)(x3 - (float)h3);
    }

    f32x4 acc[4];
    #pragma unroll
    for (int nt = 0; nt < 4; ++nt) {
        f32x4 c = {0.f, 0.f, 0.f, 0.f};
        #pragma unroll
        for (int kk = 0; kk < 4; ++kk) {
            bf16x8 b = *(const bf16x8*)(w1f + ((nt * 4 + kk) * 64 + lane) * 8);
            c = __builtin_amdgcn_mfma_f32_16x16x32_bf16(ah[kk], b, c, 0, 0, 0);
            c = __builtin_amdgcn_mfma_f32_16x16x32_bf16(al[kk], b, c, 0, 0, 0);
        }
        acc[nt] = c;
    }
    bf16_t* hb = hf[wave];
    epi_to_frag(acc, cu1, hb, lrow, quad);

    bf16x8 ha0 = *(const bf16x8*)(hb + lane * 8);
    bf16x8 ha1 = *(const bf16x8*)(hb + (lane + 64) * 8);
    gemm64(w2f, 0, ha0, ha1, acc, lane);

    #pragma unroll
    for (int nt = 0; nt < 4; ++nt) {
        int col = nt * 16 + lrow;
        float bb = cu2[col];
        #pragma unroll
        for (int r = 0; r < 4; ++r) {
            int row = nbase + quad * 4 + r;
            if (row < NN)
                out[(size_t)row * 64 + col] = gelu_f(acc[nt][r] + bb);
        }
    }
}

// ---------------- launch ----------------
extern "C" void kernel_launch(void* const* d_in, const int* in_sizes, int n_in,
                              void* d_out, int out_size, void* d_ws, size_t ws_size,
                              hipStream_t stream) {
    const float* node_feats = (const float*)d_in[0];
    const float* edge_feats = (const float*)d_in[1];
    const int*   src        = (const int*)d_in[2];
    const int*   dst        = (const int*)d_in[3];

    char* ws = (char*)d_ws;
    const bool csr = ws_size >= (size_t)116500000;

    size_t off = 0;
    bf16_t* buf = nullptr; float* agg = nullptr; int* pos = nullptr; bf16_t* msg = nullptr;
    float* s_acc = nullptr; int* cnt = nullptr; int* woff = nullptr;
    int* part = nullptr; int* btot = nullptr;

    if (csr) {
        buf = (bf16_t*)(ws + off); off += (size_t)NE * 128;    // 102,400,000
        char* aggbase = ws + off;
        agg = (float*)aggbase;     off += (size_t)NN * 256;    //  12,800,000
        pos = (int*)aggbase;                                   // alias [0, 3.2MB) — dead before agg write
        msg = (bf16_t*)(aggbase + (size_t)NE * 4);             // alias [3.2MB, 9.6MB) — dead before agg write
        cnt  = (int*)(ws + off); off += (size_t)NN * 4;
        woff = (int*)(ws + off); off += (size_t)NN * 4;
        part = (int*)(ws + off); off += (size_t)NN * 4;
        btot = (int*)(ws + off); off += 1024;
    } else {
        s_acc = (float*)(ws + off);  off += (size_t)NN * 256;
        cnt   = (int*)(ws + off);    off += (size_t)NN * 4;
        msg   = (bf16_t*)(ws + off); off += (size_t)NN * 128;
    }
    bf16_t* wcat = (bf16_t*)(ws + off); off += 32768;
    bf16_t* uW1f = (bf16_t*)(ws + off); off += 16384;
    bf16_t* uW2f = (bf16_t*)(ws + off); off += 8192;
    float* cm1 = (float*)(ws + off); off += 256;
    float* cm2 = (float*)(ws + off); off += 256;
    float* ce1 = (float*)(ws + off); off += 256;
    float* ce2 = (float*)(ws + off); off += 256;
    float* cu1 = (float*)(ws + off); off += 256;
    float* cu2 = (float*)(ws + off); off += 256;

    if (csr) {
        hipMemsetAsync(cnt, 0, (size_t)NN * 4, stream);
    } else {
        hipMemsetAsync(s_acc, 0, (size_t)NN * 256 + (size_t)NN * 4, stream);
    }

    fold_kernel<<<6, 256, 0, stream>>>(
        (const float*)d_in[4],  (const float*)d_in[5],  (const float*)d_in[6],  (const float*)d_in[7],
        (const float*)d_in[8],  (const float*)d_in[9],
        (const float*)d_in[10], (const float*)d_in[11], (const float*)d_in[12], (const float*)d_in[13],
        (const float*)d_in[14], (const float*)d_in[15],
        (const float*)d_in[16], (const float*)d_in[17], (const float*)d_in[18], (const float*)d_in[19],
        (const float*)d_in[20], (const float*)d_in[21], (const float*)d_in[22], (const float*)d_in[23],
        (const float*)d_in[24], (const float*)d_in[25],
        (const float*)d_in[26], (const float*)d_in[27], (const float*)d_in[28], (const float*)d_in[29],
        (const float*)d_in[30], (const float*)d_in[31],
        wcat, uW1f, uW2f, cm1, cm2, ce1, ce2, cu1, cu2);

    node_msg_kernel<<<(NN + 63) / 64, 256, 0, stream>>>(node_feats, wcat, cm1, cm2, msg);

    hist_kernel<<<(NE + 255) / 256, 256, 0, stream>>>(src, cnt);

    if (csr) {
        const int NBLK = (NN + 255) / 256;   // 196
        scanA_kernel<<<NBLK, 256, 0, stream>>>(cnt, part, btot);
        scanB_kernel<<<1, 256, 0, stream>>>(btot, NBLK);
        scanC_kernel<<<NBLK, 256, 0, stream>>>(part, btot, woff);
        fill_kernel<<<(NE + 255) / 256, 256, 0, stream>>>(src, woff, pos);
    }

    edge_kernel<<<NE / 64, 256, 0, stream>>>(
        edge_feats, src, dst, pos, wcat, ce1, ce2, msg, s_acc, buf, csr ? 1 : 0);

    if (csr) {
        agg_kernel<<<NN / 4, 256, 0, stream>>>(buf, woff, cnt, agg);
        update_kernel<<<(NN + 63) / 64, 256, 0, stream>>>(
            node_feats, agg, nullptr, uW1f, cu1, uW2f, cu2, (float*)d_out);
    } else {
        update_kernel<<<(NN + 63) / 64, 256, 0, stream>>>(
            node_feats, s_acc, cnt, uW1f, cu1, uW2f, cu2, (float*)d_out);
    }
}